// Round 11
// baseline (789.521 us; speedup 1.0000x reference)
//
#include <hip/hip_runtime.h>
#include <math.h>

#define R_ROWS 1048576
#define F_IN   64
#define H1     256
#define D      128
#define NN     100000
#define NE     1600000
#define NB     4096
#define A1     256
#define NTOK   16
#define N_GIN  4
#define FE_ROWS 64

typedef short short8 __attribute__((ext_vector_type(8)));
typedef float f32x4  __attribute__((ext_vector_type(4)));
typedef unsigned int uintx4 __attribute__((ext_vector_type(4)));

__device__ __forceinline__ ushort f2bf(float x) {
    uint u = __builtin_bit_cast(uint, x);
    u += 0x7FFFu + ((u >> 16) & 1u);
    return (ushort)(u >> 16);
}
__device__ __forceinline__ float bf2f(ushort h) {
    uint u = ((uint)h) << 16;
    return __builtin_bit_cast(float, u);
}
__device__ __forceinline__ uint cvtpk(float lo, float hi) {
    uint r;
    asm("v_cvt_pk_bf16_f32 %0, %1, %2" : "=v"(r) : "v"(lo), "v"(hi));
    return r;
}
__device__ __forceinline__ float lo16f(uint p) { return __builtin_bit_cast(float, p << 16); }
__device__ __forceinline__ float hi16f(uint p) { return __builtin_bit_cast(float, p & 0xFFFF0000u); }

__device__ __forceinline__ f32x4 mm(short8 a, short8 b, f32x4 c) {
    return __builtin_amdgcn_mfma_f32_16x16x32_bf16(a, b, c, 0, 0, 0);
}
__device__ __forceinline__ void acc_add(f32x4& L, f32x4& H, const uintx4 p) {
    L[0] += lo16f(p[0]); H[0] += hi16f(p[0]);
    L[1] += lo16f(p[1]); H[1] += hi16f(p[1]);
    L[2] += lo16f(p[2]); H[2] += hi16f(p[2]);
    L[3] += lo16f(p[3]); H[3] += hi16f(p[3]);
}
// 8 consecutive f32 -> short8 bf16 (hi plane)
__device__ __forceinline__ short8 load_bf8(const float* __restrict__ p) {
    const float4 v0 = *reinterpret_cast<const float4*>(p);
    const float4 v1 = *reinterpret_cast<const float4*>(p + 4);
    uintx4 pk;
    pk[0] = cvtpk(v0.x, v0.y); pk[1] = cvtpk(v0.z, v0.w);
    pk[2] = cvtpk(v1.x, v1.y); pk[3] = cvtpk(v1.z, v1.w);
    return __builtin_bit_cast(short8, pk);
}

// ---------------------------------------------------------------------------
// Pack [K][N] f32 weight into MFMA fragment order, bf16 hi/lo planes.
// ---------------------------------------------------------------------------
__device__ __forceinline__ void pack_one(const float* __restrict__ W, int Ndim,
                                         int f, int lane, ushort* __restrict__ out)
{
    const int NTn = Ndim >> 4;
    const int kt = f / NTn, nt = f - kt * NTn;
    const int k0 = kt * 32 + (lane >> 4) * 8;
    const int n = nt * 16 + (lane & 15);
    uintx4 Hv, Lv;
    #pragma unroll
    for (int jj = 0; jj < 4; ++jj) {
        const float x0 = W[(k0 + 2 * jj) * Ndim + n];
        const float x1 = W[(k0 + 2 * jj + 1) * Ndim + n];
        const ushort h0 = f2bf(x0), l0 = f2bf(x0 - bf2f(h0));
        const ushort h1u = f2bf(x1), l1 = f2bf(x1 - bf2f(h1u));
        Hv[jj] = (uint)h0 | ((uint)h1u << 16);
        Lv[jj] = (uint)l0 | ((uint)l1 << 16);
    }
    *reinterpret_cast<uintx4*>(&out[((f * 2 + 0) * 64 + lane) * 8]) = Hv;
    *reinterpret_cast<uintx4*>(&out[((f * 2 + 1) * 64 + lane) * 8]) = Lv;
}

// Pack W1(0-31), W2(32-95), gin(96-223), Wa1(224-287), Wc1(288-351),
// Wa2(352-359); remaining blocks zero deg.
__global__ __launch_bounds__(256) void pack_all(
    const float* __restrict__ W1, const float* __restrict__ W2,
    const float* __restrict__ ginW, const float* __restrict__ Wa1,
    const float* __restrict__ Wc1, const float* __restrict__ Wa2,
    ushort* __restrict__ W1p, ushort* __restrict__ W2p, ushort* __restrict__ Gp,
    ushort* __restrict__ Wa1p, ushort* __restrict__ Wc1p, ushort* __restrict__ Wa2p,
    int* __restrict__ deg)
{
    const int bid = blockIdx.x;
    if (bid < 90) {
        const int fid = bid * 4 + (threadIdx.x >> 6);
        const int lane = threadIdx.x & 63;
        if (fid < 32) pack_one(W1, H1, fid, lane, W1p);
        else if (fid < 96) pack_one(W2, D, fid - 32, lane, W2p);
        else if (fid < 224) {
            const int l = (fid - 96) >> 5;
            pack_one(ginW + (long)l * D * D, D, (fid - 96) & 31, lane, Gp + (long)l * 32768);
        } else if (fid < 288) pack_one(Wa1, A1, fid - 224, lane, Wa1p);
        else if (fid < 352) pack_one(Wc1, A1, fid - 288, lane, Wc1p);
        else if (fid < 360) pack_one(Wa2, NTOK, fid - 352, lane, Wa2p);
    } else {
        const int zb = bid - 90;
        const int idx0 = (zb * 256 + threadIdx.x) * 4;
        #pragma unroll
        for (int k = 0; k < 4; ++k) {
            const int idx = idx0 + k;
            if (idx < NN) deg[idx] = 0;
        }
    }
}

// ---------------------------------------------------------------------------
// Fused FE + segment sum. 64 rows/block, 4 waves, 4 blocks/CU (33792 B LDS).
// L1: B-fragments loaded direct from global (in-register cvtpk), W1-hi only.
// L2: W2-hi only.
// ---------------------------------------------------------------------------
__global__ __launch_bounds__(256, 4) void fe_mfma(
    const float* __restrict__ bulk, const int* __restrict__ seg,
    const ushort* __restrict__ W1p, const float* __restrict__ b1,
    const ushort* __restrict__ W2p, const float* __restrict__ b2,
    float* __restrict__ sums)
{
    __shared__ __align__(16) uint smem_u[8448];       // 33792 B
    char*  h1b = (char*)smem_u;                       // 32 KB: [64][256] bf16, XOR-swz
    float* h2  = (float*)smem_u;                      // [64][132] f32 overlay (post-L2)

    const int t = threadIdx.x;
    const int lane = t & 63;
    const int w = t >> 6;
    const long r0 = (long)blockIdx.x * FE_ROWS;

    // ---- L1 (transposed): A = W1 hi frags, B = bulk direct-from-global ----
    const f32x4 zz = {0.f, 0.f, 0.f, 0.f};
    f32x4 acc1[4][4];
    #pragma unroll
    for (int mtl = 0; mtl < 4; ++mtl)
        #pragma unroll
        for (int ntb = 0; ntb < 4; ++ntb) acc1[mtl][ntb] = zz;

    #pragma unroll
    for (int kt = 0; kt < 2; ++kt) {
        short8 aw[4];
        #pragma unroll
        for (int mtl = 0; mtl < 4; ++mtl) {
            const int f = kt * 16 + (w * 4 + mtl);
            aw[mtl] = *reinterpret_cast<const short8*>(&W1p[((f * 2 + 0) * 64 + lane) * 8]);
        }
        short8 bh[4];
        #pragma unroll
        for (int ntb = 0; ntb < 4; ++ntb) {
            const int row = ntb * 16 + (lane & 15);
            const int k0 = kt * 32 + (lane >> 4) * 8;
            bh[ntb] = load_bf8(&bulk[(r0 + row) * F_IN + k0]);
        }
        #pragma unroll
        for (int mtl = 0; mtl < 4; ++mtl)
            #pragma unroll
            for (int ntb = 0; ntb < 4; ++ntb)
                acc1[mtl][ntb] = mm(aw[mtl], bh[ntb], acc1[mtl][ntb]);
    }

    // ---- h1 store: single bf16 plane, row-major, 16B XOR swizzle ----
    #pragma unroll
    for (int mtl = 0; mtl < 4; ++mtl) {
        const int hcb = w * 64 + mtl * 16 + (lane >> 4) * 4;
        const float4 bv = *reinterpret_cast<const float4*>(&b1[hcb]);
        #pragma unroll
        for (int ntb = 0; ntb < 4; ++ntb) {
            const int hr = (lane & 15) + ntb * 16;
            const float v0 = fmaxf(acc1[mtl][ntb][0] + bv.x, 0.f);
            const float v1 = fmaxf(acc1[mtl][ntb][1] + bv.y, 0.f);
            const float v2 = fmaxf(acc1[mtl][ntb][2] + bv.z, 0.f);
            const float v3 = fmaxf(acc1[mtl][ntb][3] + bv.w, 0.f);
            uint2 pk; pk.x = cvtpk(v0, v1); pk.y = cvtpk(v2, v3);
            const int byteoff = (hr * 512 + hcb * 2) ^ ((hr & 7) << 4);
            *reinterpret_cast<uint2*>(h1b + byteoff) = pk;
        }
    }
    __syncthreads();

    // ---- L2: h2 = relu(h1 @ W2 + b2), W2-hi only ----
    float b2v[2];
    #pragma unroll
    for (int ntl = 0; ntl < 2; ++ntl) b2v[ntl] = b2[w * 32 + ntl * 16 + (lane & 15)];
    f32x4 acc2[4][2];
    #pragma unroll
    for (int mt = 0; mt < 4; ++mt) { acc2[mt][0] = zz; acc2[mt][1] = zz; }

    #pragma unroll
    for (int kt = 0; kt < 8; ++kt) {
        short8 bw2[2];
        #pragma unroll
        for (int ntl = 0; ntl < 2; ++ntl) {
            const int f = kt * 8 + (w * 2 + ntl);
            bw2[ntl] = *reinterpret_cast<const short8*>(&W2p[((f * 2 + 0) * 64 + lane) * 8]);
        }
        short8 ah[4];
        #pragma unroll
        for (int mt = 0; mt < 4; ++mt) {
            const int row = mt * 16 + (lane & 15);
            const int k0 = kt * 32 + (lane >> 4) * 8;
            ah[mt] = *reinterpret_cast<const short8*>(h1b + ((row * 512 + k0 * 2) ^ ((row & 7) << 4)));
        }
        #pragma unroll
        for (int mt = 0; mt < 4; ++mt)
            #pragma unroll
            for (int ntl = 0; ntl < 2; ++ntl)
                acc2[mt][ntl] = mm(ah[mt], bw2[ntl], acc2[mt][ntl]);
    }
    __syncthreads();   // all h1 reads done before h2 overlays LDS

    #pragma unroll
    for (int mt = 0; mt < 4; ++mt)
        #pragma unroll
        for (int ntl = 0; ntl < 2; ++ntl)
            #pragma unroll
            for (int r = 0; r < 4; ++r) {
                const int row = mt * 16 + (lane >> 4) * 4 + r;
                const int col = w * 32 + ntl * 16 + (lane & 15);
                h2[row * 132 + col] = fmaxf(acc2[mt][ntl][r] + b2v[ntl], 0.f);
            }
    __syncthreads();

    // ---- segment sums: 2 half-windows x 128 cols ----
    {
        const int g = t >> 7;
        const int c = t & 127;
        const int base = g * 32;
        const long rb = r0 + base;
        const int prev = (rb == 0) ? -1 : seg[rb - 1];
        const int nxt = (rb + 32 >= R_ROWS) ? -1 : seg[rb + 32];
        int cur = seg[rb];
        float run = 0.f;
        int runstart = 0;
        #pragma unroll 1
        for (int r = 0; r < 32; ++r) {
            const int s = seg[rb + r];
            if (s != cur) {
                if (runstart != 0 || cur != prev) sums[(long)cur * D + c] = run;
                else atomicAdd(&sums[(long)cur * D + c], run);
                cur = s; run = 0.f; runstart = r;
            }
            run += h2[(base + r) * 132 + c];
        }
        if ((runstart != 0 || cur != prev) && cur != nxt) sums[(long)cur * D + c] = run;
        else atomicAdd(&sums[(long)cur * D + c], run);
    }
}

__global__ __launch_bounds__(256) void start_kernel(const int* __restrict__ seg,
                                                    int* __restrict__ start)
{
    const int n = blockIdx.x * 256 + threadIdx.x;
    if (n > NN) return;
    int lo = 0, hi = R_ROWS;
    #pragma unroll 1
    while (lo < hi) {
        const int mid = (lo + hi) >> 1;
        if (seg[mid] < n) lo = mid + 1; else hi = mid;
    }
    start[n] = lo;
}

__global__ __launch_bounds__(256) void divide_bf(
    const float* __restrict__ sums, const int* __restrict__ start,
    uint* __restrict__ hbf)
{
    const long i = (long)blockIdx.x * 256 + threadIdx.x;
    if (i < (long)NN * 64) {
        const int n = (int)(i >> 6), u = (int)(i & 63);
        const int cA = (u & 15) + (u >> 4) * 32;
        const float inv = 1.f / fmaxf((float)(start[n + 1] - start[n]), 1.f);
        const float vA = sums[(long)n * D + cA] * inv;
        const float vB = sums[(long)n * D + cA + 16] * inv;
        hbf[i] = cvtpk(vA, vB);
    }
}

__global__ __launch_bounds__(256) void hist_kernel(const int* __restrict__ edst,
                                                   int* __restrict__ deg)
{
    const int e = blockIdx.x * 256 + threadIdx.x;
    if (e < NE) atomicAdd(&deg[edst[e]], 1);
}

#define SCHUNK 2048
__global__ __launch_bounds__(256) void scan_reduce(const int* __restrict__ deg,
                                                   int* __restrict__ partials, int n)
{
    __shared__ int sdata[256];
    const int b = blockIdx.x, t = threadIdx.x;
    const int base = b * SCHUNK;
    int sum = 0;
    for (int i = t; i < SCHUNK; i += 256) {
        const int idx = base + i;
        sum += (idx < n) ? deg[idx] : 0;
    }
    sdata[t] = sum; __syncthreads();
    for (int s = 128; s > 0; s >>= 1) {
        if (t < s) sdata[t] += sdata[t + s];
        __syncthreads();
    }
    if (t == 0) partials[b] = sdata[0];
}

__global__ __launch_bounds__(256) void scan_write(const int* __restrict__ deg,
                                                  const int* __restrict__ partials,
                                                  int nchunks,
                                                  int* __restrict__ offsets,
                                                  int* __restrict__ cursor, int n)
{
    __shared__ int sdata[256];
    __shared__ int base_sh;
    const int b = blockIdx.x, t = threadIdx.x;
    if (t < 64) {
        int v = (t < b && t < nchunks) ? partials[t] : 0;
        #pragma unroll
        for (int d2 = 1; d2 < 64; d2 <<= 1) v += __shfl_xor(v, d2);
        if (t == 0) base_sh = v;
    }
    const int base = b * SCHUNK;
    int loc[8]; int s = 0;
    #pragma unroll
    for (int j = 0; j < 8; ++j) {
        const int idx = base + t * 8 + j;
        const int v = (idx < n) ? deg[idx] : 0;
        loc[j] = s; s += v;
    }
    sdata[t] = s; __syncthreads();
    for (int d = 1; d < 256; d <<= 1) {
        const int v = (t >= d) ? sdata[t - d] : 0;
        __syncthreads();
        sdata[t] += v;
        __syncthreads();
    }
    const int excl = (t == 0) ? 0 : sdata[t - 1];
    const int tbase = base_sh + excl;
    #pragma unroll
    for (int j = 0; j < 8; ++j) {
        const int idx = base + t * 8 + j;
        if (idx < n) {
            const int o = tbase + loc[j];
            offsets[idx] = o;
            cursor[idx] = o;
        }
    }
}

__global__ __launch_bounds__(256) void scatter_edges(const int* __restrict__ esrc,
                                                     const int* __restrict__ edst,
                                                     int* __restrict__ cursor,
                                                     int* __restrict__ csr_src)
{
    const int e = blockIdx.x * 256 + threadIdx.x;
    if (e < NE) {
        const int d = edst[e];
        const int p = atomicAdd(&cursor[d], 1);
        csr_src[p] = esrc[e];
    }
}

// ---------------------------------------------------------------------------
// Fused GIN layer, bf16 h. Half-wave per row gather; W-hi-only MFMA.
// MODE 0: all nodes -> hbf; MODE 2: roots -> compact X buffer.
// ---------------------------------------------------------------------------
template<int MODE>
__global__ __launch_bounds__(256, 8) void gin_kernel(
    const uint* __restrict__ hbf, const int* __restrict__ offsets,
    const int* __restrict__ deg, const int* __restrict__ csr,
    const ushort* __restrict__ Wp, const float* __restrict__ bvec,
    uint* __restrict__ outbuf, const int* __restrict__ root)
{
    __shared__ __align__(16) char ylds[64 * 256];   // 16 KB
    const int t = threadIdx.x, lane = t & 63, w = t >> 6;
    const int h = lane >> 5;
    const int q2 = (lane >> 4) & 1;
    const int m = lane & 15;
    const int q = lane >> 4;
    const int r0 = blockIdx.x * 64;

    #pragma unroll 1
    for (int i = 0; i < 8; ++i) {
        const int row = w * 16 + i * 2 + h;
        int n = -1;
        if (MODE == 0) {
            const int nn = r0 + row;
            if (nn < NN) n = nn;
        } else {
            n = root[r0 + row];
        }
        f32x4 accL = {0.f, 0.f, 0.f, 0.f};
        f32x4 accH = {0.f, 0.f, 0.f, 0.f};
        if (n >= 0) {
            const uintx4 sp = *reinterpret_cast<const uintx4*>(&hbf[(long)n * 64 + 4 * m]);
            const float sc = (q2 == 0) ? 2.1f : 0.f;
            accL[0] = sc * lo16f(sp[0]); accH[0] = sc * hi16f(sp[0]);
            accL[1] = sc * lo16f(sp[1]); accH[1] = sc * hi16f(sp[1]);
            accL[2] = sc * lo16f(sp[2]); accH[2] = sc * hi16f(sp[2]);
            accL[3] = sc * lo16f(sp[3]); accH[3] = sc * hi16f(sp[3]);
            const int off = offsets[n];
            const int dg = deg[n];
            const int dg2 = dg >> 1;
            int jj = 0;
            for (; jj + 4 <= dg2; jj += 4) {
                const int b0 = off + 2 * jj + q2;
                const int s0 = csr[b0], s1 = csr[b0 + 2], s2 = csr[b0 + 4], s3 = csr[b0 + 6];
                const uintx4 p0 = *reinterpret_cast<const uintx4*>(&hbf[(long)s0 * 64 + 4 * m]);
                const uintx4 p1 = *reinterpret_cast<const uintx4*>(&hbf[(long)s1 * 64 + 4 * m]);
                const uintx4 p2 = *reinterpret_cast<const uintx4*>(&hbf[(long)s2 * 64 + 4 * m]);
                const uintx4 p3 = *reinterpret_cast<const uintx4*>(&hbf[(long)s3 * 64 + 4 * m]);
                acc_add(accL, accH, p0);
                acc_add(accL, accH, p1);
                acc_add(accL, accH, p2);
                acc_add(accL, accH, p3);
            }
            for (; jj < dg2; ++jj) {
                const int s = csr[off + 2 * jj + q2];
                const uintx4 p = *reinterpret_cast<const uintx4*>(&hbf[(long)s * 64 + 4 * m]);
                acc_add(accL, accH, p);
            }
            if ((dg & 1) && q2 == 0) {
                const int s = csr[off + dg - 1];
                const uintx4 p = *reinterpret_cast<const uintx4*>(&hbf[(long)s * 64 + 4 * m]);
                acc_add(accL, accH, p);
            }
        }
        #pragma unroll
        for (int e = 0; e < 4; ++e) {
            accL[e] += __shfl_xor(accL[e], 16);
            accH[e] += __shfl_xor(accH[e], 16);
        }
        const int swz = (row & 7) << 4;
        #pragma unroll
        for (int e = 0; e < 2; ++e) {
            const int u = 4 * m + 2 * q2 + e;
            const int cA = (u & 15) + (u >> 4) * 32;
            const uint pk = cvtpk(accL[2 * q2 + e], accH[2 * q2 + e]);
            *reinterpret_cast<ushort*>(ylds + ((row * 256 + cA * 2) ^ swz)) = (ushort)pk;
            *reinterpret_cast<ushort*>(ylds + ((row * 256 + (cA + 16) * 2) ^ swz)) = (ushort)(pk >> 16);
        }
    }

    short8 bw0[2];
    #pragma unroll
    for (int ntl = 0; ntl < 2; ++ntl) {
        const int f = w * 2 + ntl;
        bw0[ntl] = *reinterpret_cast<const short8*>(&Wp[((f * 2 + 0) * 64 + lane) * 8]);
    }
    __syncthreads();

    const f32x4 zz = {0.f, 0.f, 0.f, 0.f};
    f32x4 acc[4][2];
    #pragma unroll
    for (int mt = 0; mt < 4; ++mt) { acc[mt][0] = zz; acc[mt][1] = zz; }

    #pragma unroll
    for (int kt = 0; kt < 4; ++kt) {
        short8 bw[2];
        if (kt == 0) { bw[0] = bw0[0]; bw[1] = bw0[1]; }
        else {
            #pragma unroll
            for (int ntl = 0; ntl < 2; ++ntl) {
                const int f = kt * 8 + (w * 2 + ntl);
                bw[ntl] = *reinterpret_cast<const short8*>(&Wp[((f * 2 + 0) * 64 + lane) * 8]);
            }
        }
        #pragma unroll
        for (int mt = 0; mt < 4; ++mt) {
            const int row = mt * 16 + m;
            const int k0 = kt * 32 + q * 8;
            const short8 ah = *reinterpret_cast<const short8*>(
                ylds + ((row * 256 + k0 * 2) ^ ((row & 7) << 4)));
            acc[mt][0] = mm(ah, bw[0], acc[mt][0]);
            acc[mt][1] = mm(ah, bw[1], acc[mt][1]);
        }
    }

    const float bv0 = bvec[w * 32 + m];
    const float bv1 = bvec[w * 32 + 16 + m];
    #pragma unroll
    for (int mt = 0; mt < 4; ++mt)
        #pragma unroll
        for (int r = 0; r < 4; ++r) {
            const int grow_row = mt * 16 + q * 4 + r;
            const float v0 = fmaxf(acc[mt][0][r] + bv0, 0.f);
            const float v1 = fmaxf(acc[mt][1][r] + bv1, 0.f);
            const uint pk = cvtpk(v0, v1);
            if (MODE == 0) {
                const long nout = r0 + grow_row;
                if (nout < NN) outbuf[nout * 64 + w * 16 + m] = pk;
            } else {
                outbuf[(long)(r0 + grow_row) * 64 + w * 16 + m] = pk;
            }
        }
}

// ---------------------------------------------------------------------------
// MFMA batch heads: 64 blocks x 64 roots. Full hi+lo split for head weights.
// ---------------------------------------------------------------------------
__global__ __launch_bounds__(256) void head_mfma(
    const uint* __restrict__ Xbf,
    const ushort* __restrict__ Wa1p, const float* __restrict__ ba1,
    const ushort* __restrict__ Wa2p, const float* __restrict__ ba2,
    const ushort* __restrict__ Wc1p, const float* __restrict__ bc1,
    const float* __restrict__ Wc2, const float* __restrict__ bc2,
    float* __restrict__ out_act, float* __restrict__ out_crit)
{
    __shared__ __align__(16) char Xp[64 * 256];    // 16 KB
    __shared__ __align__(16) char a1p[64 * 512];   // 32 KB
    const int t = threadIdx.x, lane = t & 63, w = t >> 6;
    const int r0 = blockIdx.x * 64;
    const f32x4 zz = {0.f, 0.f, 0.f, 0.f};

    {
        const int row = t >> 2;
        const int ug = (t & 3) * 16;
        const int swz = (row & 7) << 4;
        #pragma unroll
        for (int uu = 0; uu < 16; ++uu) {
            const uint pk = Xbf[(long)(r0 + row) * 64 + ug + uu];
            const int u = ug + uu;
            const int cA = (u & 15) + (u >> 4) * 32;
            *reinterpret_cast<ushort*>(Xp + ((row * 256 + cA * 2) ^ swz)) = (ushort)pk;
            *reinterpret_cast<ushort*>(Xp + ((row * 256 + (cA + 16) * 2) ^ swz)) = (ushort)(pk >> 16);
        }
    }
    __syncthreads();

    {
        f32x4 acc1[4][4];
        #pragma unroll
        for (int mtl = 0; mtl < 4; ++mtl)
            #pragma unroll
            for (int ntb = 0; ntb < 4; ++ntb) acc1[mtl][ntb] = zz;
        #pragma unroll
        for (int kt = 0; kt < 4; ++kt) {
            short8 aw[4][2];
            #pragma unroll
            for (int mtl = 0; mtl < 4; ++mtl)
                #pragma unroll
                for (int p = 0; p < 2; ++p) {
                    const int f = kt * 16 + (w * 4 + mtl);
                    aw[mtl][p] = *reinterpret_cast<const short8*>(&Wa1p[((f * 2 + p) * 64 + lane) * 8]);
                }
            short8 bh[4];
            #pragma unroll
            for (int ntb = 0; ntb < 4; ++ntb) {
                const int row = ntb * 16 + (lane & 15);
                const int k0 = kt * 32 + (lane >> 4) * 8;
                bh[ntb] = *reinterpret_cast<const short8*>(Xp + ((row * 256 + k0 * 2) ^ ((row & 7) << 4)));
            }
            #pragma unroll
            for (int mtl = 0; mtl < 4; ++mtl)
                #pragma unroll
                for (int ntb = 0; ntb < 4; ++ntb) {
                    acc1[mtl][ntb] = mm(aw[mtl][0], bh[ntb], acc1[mtl][ntb]);
                    acc1[mtl][ntb] = mm(aw[mtl][1], bh[ntb], acc1[mtl][ntb]);
                }
        }
        #pragma unroll
        for (int mtl = 0; mtl < 4; ++mtl) {
            const int hcb = w * 64 + mtl * 16 + (lane >> 4) * 4;
            const float4 bv = *reinterpret_cast<const float4*>(&ba1[hcb]);
            #pragma unroll
            for (int ntb = 0; ntb < 4; ++ntb) {
                const int hr = (lane & 15) + ntb * 16;
                const float v0 = fmaxf(acc1[mtl][ntb][0] + bv.x, 0.f);
                const float v1 = fmaxf(acc1[mtl][ntb][1] + bv.y, 0.f);
                const float v2 = fmaxf(acc1[mtl][ntb][2] + bv.z, 0.f);
                const float v3 = fmaxf(acc1[mtl][ntb][3] + bv.w, 0.f);
                uint2 pk; pk.x = cvtpk(v0, v1); pk.y = cvtpk(v2, v3);
                const int byteoff = (hr * 512 + hcb * 2) ^ ((hr & 7) << 4);
                *reinterpret_cast<uint2*>(a1p + byteoff) = pk;
            }
        }
    }
    __syncthreads();

    {
        f32x4 accl = zz;
        #pragma unroll
        for (int kt = 0; kt < 8; ++kt) {
            short8 b2h = *reinterpret_cast<const short8*>(&Wa2p[((kt * 2 + 0) * 64 + lane) * 8]);
            short8 b2l = *reinterpret_cast<const short8*>(&Wa2p[((kt * 2 + 1) * 64 + lane) * 8]);
            const int row = w * 16 + (lane & 15);
            const int k0 = kt * 32 + (lane >> 4) * 8;
            const short8 ah = *reinterpret_cast<const short8*>(a1p + ((row * 512 + k0 * 2) ^ ((row & 7) << 4)));
            accl = mm(ah, b2h, accl);
            accl = mm(ah, b2l, accl);
        }
        const int j = lane & 15;
        float lg[4], sm[4];
        #pragma unroll
        for (int r = 0; r < 4; ++r) {
            lg[r] = fmaxf(accl[r] + ba2[j], 0.f);
            float m2 = lg[r];
            #pragma unroll
            for (int d2 = 1; d2 < 16; d2 <<= 1) m2 = fmaxf(m2, __shfl_xor(m2, d2));
            lg[r] = expf(lg[r] - m2);
            float s2 = lg[r];
            #pragma unroll
            for (int d2 = 1; d2 < 16; d2 <<= 1) s2 += __shfl_xor(s2, d2);
            sm[r] = s2;
        }
        #pragma unroll
        for (int r = 0; r < 4; ++r) {
            const int root_slot = r0 + w * 16 + (lane >> 4) * 4 + r;
            out_act[(long)root_slot * NTOK + j] = lg[r] / sm[r];
        }
    }
    __syncthreads();

    {
        f32x4 acc1[4][4];
        #pragma unroll
        for (int mtl = 0; mtl < 4; ++mtl)
            #pragma unroll
            for (int ntb = 0; ntb < 4; ++ntb) acc1[mtl][ntb] = zz;
        #pragma unroll
        for (int kt = 0; kt < 4; ++kt) {
            short8 aw[4][2];
            #pragma unroll
            for (int mtl = 0; mtl < 4; ++mtl)
                #pragma unroll
                for (int p = 0; p < 2; ++p) {
                    const int f = kt * 16 + (w * 4 + mtl);
                    aw[mtl][p] = *reinterpret_cast<const short8*>(&Wc1p[((f * 2 + p) * 64 + lane) * 8]);
                }
            short8 bh[4];
            #pragma unroll
            for (int ntb = 0; ntb < 4; ++ntb) {
                const int row = ntb * 16 + (lane & 15);
                const int k0 = kt * 32 + (lane >> 4) * 8;
                bh[ntb] = *reinterpret_cast<const short8*>(Xp + ((row * 256 + k0 * 2) ^ ((row & 7) << 4)));
            }
            #pragma unroll
            for (int mtl = 0; mtl < 4; ++mtl)
                #pragma unroll
                for (int ntb = 0; ntb < 4; ++ntb) {
                    acc1[mtl][ntb] = mm(aw[mtl][0], bh[ntb], acc1[mtl][ntb]);
                    acc1[mtl][ntb] = mm(aw[mtl][1], bh[ntb], acc1[mtl][ntb]);
                }
        }
        #pragma unroll
        for (int mtl = 0; mtl < 4; ++mtl) {
            const int hcb = w * 64 + mtl * 16 + (lane >> 4) * 4;
            const float4 bv = *reinterpret_cast<const float4*>(&bc1[hcb]);
            #pragma unroll
            for (int ntb = 0; ntb < 4; ++ntb) {
                const int hr = (lane & 15) + ntb * 16;
                const float v0 = fmaxf(acc1[mtl][ntb][0] + bv.x, 0.f);
                const float v1 = fmaxf(acc1[mtl][ntb][1] + bv.y, 0.f);
                const float v2 = fmaxf(acc1[mtl][ntb][2] + bv.z, 0.f);
                const float v3 = fmaxf(acc1[mtl][ntb][3] + bv.w, 0.f);
                uint2 pk; pk.x = cvtpk(v0, v1); pk.y = cvtpk(v2, v3);
                const int byteoff = (hr * 512 + hcb * 2) ^ ((hr & 7) << 4);
                *reinterpret_cast<uint2*>(a1p + byteoff) = pk;
            }
        }
    }
    __syncthreads();

    {
        const int row = w * 16 + (lane & 15);
        const int qk = lane >> 4;
        float dot = 0.f;
        #pragma unroll
        for (int g = 0; g < 8; ++g) {
            const int k0 = qk * 64 + g * 8;
            const short8 av = *reinterpret_cast<const short8*>(a1p + ((row * 512 + k0 * 2) ^ ((row & 7) << 4)));
            #pragma unroll
            for (int e = 0; e < 8; ++e)
                dot = fmaf(bf2f((ushort)av[e]), Wc2[k0 + e], dot);
        }
        dot += __shfl_xor(dot, 16);
        dot += __shfl_xor(dot, 32);
        if (lane < 16) out_crit[r0 + w * 16 + lane] = dot + bc2[0];
    }
}

// ---------------------------------------------------------------------------
extern "C" void kernel_launch(void* const* d_in, const int* in_sizes, int n_in,
                              void* d_out, int out_size, void* d_ws, size_t ws_size,
                              hipStream_t stream)
{
    const float* bulk = (const float*)d_in[0];
    const int*   seg  = (const int*)d_in[1];
    const int*   esrc = (const int*)d_in[2];
    const int*   edst = (const int*)d_in[3];
    const int*   root = (const int*)d_in[4];
    const float* W1   = (const float*)d_in[6];
    const float* b1   = (const float*)d_in[7];
    const float* W2   = (const float*)d_in[8];
    const float* b2   = (const float*)d_in[9];
    const float* ginW = (const float*)d_in[10];
    const float* ginb = (const float*)d_in[11];
    const float* Wa1  = (const float*)d_in[12];
    const float* ba1  = (const float*)d_in[13];
    const float* Wa2  = (const float*)d_in[14];
    const float* ba2  = (const float*)d_in[15];
    const float* Wc1  = (const float*)d_in[16];
    const float* bc1  = (const float*)d_in[17];
    const float* Wc2  = (const float*)d_in[18];
    const float* bc2  = (const float*)d_in[19];

    char* ws = (char*)d_ws;
    ushort* W1p = (ushort*)ws;                     // 64 KB
    ushort* W2p = W1p + 32768;                     // 128 KB
    float* sums    = (float*)(ws + 196608);        // N*D f32
    uint*  hbfA    = (uint*)(sums + (long)NN * D); // N*64
    uint*  hbfB    = hbfA + (long)NN * 64;         // N*64
    int*   start   = (int*)(hbfB + (long)NN * 64); // N+4
    int*   deg     = start + (NN + 4);             // N
    int*   offsets = deg + NN;                     // N
    int*   cursor  = offsets + NN;                 // N
    int*   partials= cursor + NN;                  // 256
    int*   csr     = partials + 256;               // E
    uint*  Xbf     = (uint*)(csr + NE);            // NB*64
    ushort* Gp     = (ushort*)(Xbf + (long)NB * 64); // 256 KB
    ushort* Wa1p   = Gp + 4 * 32768;               // 128 KB
    ushort* Wc1p   = Wa1p + 65536;                 // 128 KB
    ushort* Wa2p   = Wc1p + 65536;                 // 16 KB

    hipMemsetAsync(sums, 0, (long)NN * D * sizeof(float), stream);

    pack_all<<<188, 256, 0, stream>>>(W1, W2, ginW, Wa1, Wc1, Wa2,
                                      W1p, W2p, Gp, Wa1p, Wc1p, Wa2p, deg);

    fe_mfma<<<R_ROWS / FE_ROWS, 256, 0, stream>>>(bulk, seg, W1p, b1, W2p, b2, sums);
    start_kernel<<<(NN + 256) / 256, 256, 0, stream>>>(seg, start);
    divide_bf<<<((long)NN * 64 + 255) / 256, 256, 0, stream>>>(sums, start, hbfA);

    hist_kernel<<<(NE + 255) / 256, 256, 0, stream>>>(edst, deg);
    const int nchunks = (NN + SCHUNK - 1) / SCHUNK;
    scan_reduce<<<nchunks, 256, 0, stream>>>(deg, partials, NN);
    scan_write<<<nchunks, 256, 0, stream>>>(deg, partials, nchunks, offsets, cursor, NN);
    scatter_edges<<<(NE + 255) / 256, 256, 0, stream>>>(esrc, edst, cursor, csr);

    const int full_grid = (NN + 63) / 64;
    gin_kernel<0><<<full_grid, 256, 0, stream>>>(hbfA, offsets, deg, csr,
        Gp + 0L * 32768, ginb + 0L * D, hbfB, root);
    gin_kernel<0><<<full_grid, 256, 0, stream>>>(hbfB, offsets, deg, csr,
        Gp + 1L * 32768, ginb + 1L * D, hbfA, root);
    gin_kernel<0><<<full_grid, 256, 0, stream>>>(hbfA, offsets, deg, csr,
        Gp + 2L * 32768, ginb + 2L * D, hbfB, root);
    gin_kernel<2><<<NB / 64, 256, 0, stream>>>(hbfB, offsets, deg, csr,
        Gp + 3L * 32768, ginb + 3L * D, Xbf, root);

    head_mfma<<<NB / 64, 256, 0, stream>>>(Xbf, Wa1p, ba1, Wa2p, ba2,
                                           Wc1p, bc1, Wc2, bc2,
                                           (float*)d_out, (float*)d_out + (long)NB * NTOK);
}

// Round 12
// 700.167 us; speedup vs baseline: 1.1276x; 1.1276x over previous
//
#include <hip/hip_runtime.h>
#include <math.h>

#define R_ROWS 1048576
#define F_IN   64
#define H1     256
#define D      128
#define NN     100000
#define NE     1600000
#define NB     4096
#define A1     256
#define NTOK   16
#define N_GIN  4
#define FE_ROWS 64

typedef short short8 __attribute__((ext_vector_type(8)));
typedef float f32x4  __attribute__((ext_vector_type(4)));
typedef unsigned int uintx4 __attribute__((ext_vector_type(4)));

__device__ __forceinline__ ushort f2bf(float x) {
    uint u = __builtin_bit_cast(uint, x);
    u += 0x7FFFu + ((u >> 16) & 1u);
    return (ushort)(u >> 16);
}
__device__ __forceinline__ float bf2f(ushort h) {
    uint u = ((uint)h) << 16;
    return __builtin_bit_cast(float, u);
}
__device__ __forceinline__ uint cvtpk(float lo, float hi) {
    uint r;
    asm("v_cvt_pk_bf16_f32 %0, %1, %2" : "=v"(r) : "v"(lo), "v"(hi));
    return r;
}
__device__ __forceinline__ float lo16f(uint p) { return __builtin_bit_cast(float, p << 16); }
__device__ __forceinline__ float hi16f(uint p) { return __builtin_bit_cast(float, p & 0xFFFF0000u); }

__device__ __forceinline__ f32x4 mm(short8 a, short8 b, f32x4 c) {
    return __builtin_amdgcn_mfma_f32_16x16x32_bf16(a, b, c, 0, 0, 0);
}
__device__ __forceinline__ void acc_add(f32x4& L, f32x4& H, const uintx4 p) {
    L[0] += lo16f(p[0]); H[0] += hi16f(p[0]);
    L[1] += lo16f(p[1]); H[1] += hi16f(p[1]);
    L[2] += lo16f(p[2]); H[2] += hi16f(p[2]);
    L[3] += lo16f(p[3]); H[3] += hi16f(p[3]);
}

// ---------------------------------------------------------------------------
// Pack [K][N] f32 weight into MFMA fragment order, bf16 hi/lo planes.
// ---------------------------------------------------------------------------
__device__ __forceinline__ void pack_one(const float* __restrict__ W, int Ndim,
                                         int f, int lane, ushort* __restrict__ out)
{
    const int NTn = Ndim >> 4;
    const int kt = f / NTn, nt = f - kt * NTn;
    const int k0 = kt * 32 + (lane >> 4) * 8;
    const int n = nt * 16 + (lane & 15);
    uintx4 Hv, Lv;
    #pragma unroll
    for (int jj = 0; jj < 4; ++jj) {
        const float x0 = W[(k0 + 2 * jj) * Ndim + n];
        const float x1 = W[(k0 + 2 * jj + 1) * Ndim + n];
        const ushort h0 = f2bf(x0), l0 = f2bf(x0 - bf2f(h0));
        const ushort h1u = f2bf(x1), l1 = f2bf(x1 - bf2f(h1u));
        Hv[jj] = (uint)h0 | ((uint)h1u << 16);
        Lv[jj] = (uint)l0 | ((uint)l1 << 16);
    }
    *reinterpret_cast<uintx4*>(&out[((f * 2 + 0) * 64 + lane) * 8]) = Hv;
    *reinterpret_cast<uintx4*>(&out[((f * 2 + 1) * 64 + lane) * 8]) = Lv;
}

// Pack W1(0-31), W2(32-95), gin(96-223), Wa1(224-287), Wc1(288-351),
// Wa2(352-359); remaining blocks zero deg.
__global__ __launch_bounds__(256) void pack_all(
    const float* __restrict__ W1, const float* __restrict__ W2,
    const float* __restrict__ ginW, const float* __restrict__ Wa1,
    const float* __restrict__ Wc1, const float* __restrict__ Wa2,
    ushort* __restrict__ W1p, ushort* __restrict__ W2p, ushort* __restrict__ Gp,
    ushort* __restrict__ Wa1p, ushort* __restrict__ Wc1p, ushort* __restrict__ Wa2p,
    int* __restrict__ deg)
{
    const int bid = blockIdx.x;
    if (bid < 90) {
        const int fid = bid * 4 + (threadIdx.x >> 6);
        const int lane = threadIdx.x & 63;
        if (fid < 32) pack_one(W1, H1, fid, lane, W1p);
        else if (fid < 96) pack_one(W2, D, fid - 32, lane, W2p);
        else if (fid < 224) {
            const int l = (fid - 96) >> 5;
            pack_one(ginW + (long)l * D * D, D, (fid - 96) & 31, lane, Gp + (long)l * 32768);
        } else if (fid < 288) pack_one(Wa1, A1, fid - 224, lane, Wa1p);
        else if (fid < 352) pack_one(Wc1, A1, fid - 288, lane, Wc1p);
        else if (fid < 360) pack_one(Wa2, NTOK, fid - 352, lane, Wa2p);
    } else {
        const int zb = bid - 90;
        const int idx0 = (zb * 256 + threadIdx.x) * 4;
        #pragma unroll
        for (int k = 0; k < 4; ++k) {
            const int idx = idx0 + k;
            if (idx < NN) deg[idx] = 0;
        }
    }
}

// ---------------------------------------------------------------------------
// Fused FE + segment sum. 64 rows/block, 4 waves, 4 blocks/CU (40960 B LDS).
// Coalesced bulk->LDS staging; W1-hi only; W2-hi only.
// ---------------------------------------------------------------------------
__global__ __launch_bounds__(256, 4) void fe_mfma(
    const float* __restrict__ bulk, const int* __restrict__ seg,
    const ushort* __restrict__ W1p, const float* __restrict__ b1,
    const ushort* __restrict__ W2p, const float* __restrict__ b2,
    float* __restrict__ sums)
{
    __shared__ __align__(16) uint smem_u[10240];      // 40960 B
    char* Ab  = (char*)smem_u;                        // 8 KB: [64][64] bf16, XOR-swz
    char* h1b = Ab + 8192;                            // 32 KB: [64][256] bf16, XOR-swz
    float* h2 = (float*)smem_u;                       // [64][132] f32 overlay (post-L2)

    const int t = threadIdx.x;
    const int lane = t & 63;
    const int w = t >> 6;
    const long r0 = (long)blockIdx.x * FE_ROWS;

    // ---- stage bulk rows, single bf16 plane, 16B XOR swizzle (coalesced) ----
    #pragma unroll
    for (int i = 0; i < 4; ++i) {
        const int gid = t + i * 256;
        const int row = gid >> 4;
        const int c4 = (gid & 15) * 4;
        const float4 v = *reinterpret_cast<const float4*>(&bulk[(r0 + row) * F_IN + c4]);
        uint2 pk; pk.x = cvtpk(v.x, v.y); pk.y = cvtpk(v.z, v.w);
        const int byteoff = row * 128 + ((c4 * 2) ^ ((row & 7) << 4));
        *reinterpret_cast<uint2*>(Ab + byteoff) = pk;
    }
    __syncthreads();

    // ---- L1 (transposed): A = W1 hi frags, B = bulk bf16 plane ----
    const f32x4 zz = {0.f, 0.f, 0.f, 0.f};
    f32x4 acc1[4][4];
    #pragma unroll
    for (int mtl = 0; mtl < 4; ++mtl)
        #pragma unroll
        for (int ntb = 0; ntb < 4; ++ntb) acc1[mtl][ntb] = zz;

    #pragma unroll
    for (int kt = 0; kt < 2; ++kt) {
        short8 aw[4];
        #pragma unroll
        for (int mtl = 0; mtl < 4; ++mtl) {
            const int f = kt * 16 + (w * 4 + mtl);
            aw[mtl] = *reinterpret_cast<const short8*>(&W1p[((f * 2 + 0) * 64 + lane) * 8]);
        }
        short8 bh[4];
        #pragma unroll
        for (int ntb = 0; ntb < 4; ++ntb) {
            const int row = ntb * 16 + (lane & 15);
            const int k0 = kt * 32 + (lane >> 4) * 8;
            bh[ntb] = *reinterpret_cast<const short8*>(Ab + (row * 128 + ((k0 * 2) ^ ((row & 7) << 4))));
        }
        #pragma unroll
        for (int mtl = 0; mtl < 4; ++mtl)
            #pragma unroll
            for (int ntb = 0; ntb < 4; ++ntb)
                acc1[mtl][ntb] = mm(aw[mtl], bh[ntb], acc1[mtl][ntb]);
    }

    // ---- h1 store: single bf16 plane, row-major, 16B XOR swizzle ----
    #pragma unroll
    for (int mtl = 0; mtl < 4; ++mtl) {
        const int hcb = w * 64 + mtl * 16 + (lane >> 4) * 4;
        const float4 bv = *reinterpret_cast<const float4*>(&b1[hcb]);
        #pragma unroll
        for (int ntb = 0; ntb < 4; ++ntb) {
            const int hr = (lane & 15) + ntb * 16;
            const float v0 = fmaxf(acc1[mtl][ntb][0] + bv.x, 0.f);
            const float v1 = fmaxf(acc1[mtl][ntb][1] + bv.y, 0.f);
            const float v2 = fmaxf(acc1[mtl][ntb][2] + bv.z, 0.f);
            const float v3 = fmaxf(acc1[mtl][ntb][3] + bv.w, 0.f);
            uint2 pk; pk.x = cvtpk(v0, v1); pk.y = cvtpk(v2, v3);
            const int byteoff = (hr * 512 + hcb * 2) ^ ((hr & 7) << 4);
            *reinterpret_cast<uint2*>(h1b + byteoff) = pk;
        }
    }
    __syncthreads();

    // ---- L2: h2 = relu(h1 @ W2 + b2), W2-hi only ----
    float b2v[2];
    #pragma unroll
    for (int ntl = 0; ntl < 2; ++ntl) b2v[ntl] = b2[w * 32 + ntl * 16 + (lane & 15)];
    f32x4 acc2[4][2];
    #pragma unroll
    for (int mt = 0; mt < 4; ++mt) { acc2[mt][0] = zz; acc2[mt][1] = zz; }

    #pragma unroll
    for (int kt = 0; kt < 8; ++kt) {
        short8 bw2[2];
        #pragma unroll
        for (int ntl = 0; ntl < 2; ++ntl) {
            const int f = kt * 8 + (w * 2 + ntl);
            bw2[ntl] = *reinterpret_cast<const short8*>(&W2p[((f * 2 + 0) * 64 + lane) * 8]);
        }
        short8 ah[4];
        #pragma unroll
        for (int mt = 0; mt < 4; ++mt) {
            const int row = mt * 16 + (lane & 15);
            const int k0 = kt * 32 + (lane >> 4) * 8;
            ah[mt] = *reinterpret_cast<const short8*>(h1b + ((row * 512 + k0 * 2) ^ ((row & 7) << 4)));
        }
        #pragma unroll
        for (int mt = 0; mt < 4; ++mt)
            #pragma unroll
            for (int ntl = 0; ntl < 2; ++ntl)
                acc2[mt][ntl] = mm(ah[mt], bw2[ntl], acc2[mt][ntl]);
    }
    __syncthreads();   // all h1 reads done before h2 overlays LDS

    #pragma unroll
    for (int mt = 0; mt < 4; ++mt)
        #pragma unroll
        for (int ntl = 0; ntl < 2; ++ntl)
            #pragma unroll
            for (int r = 0; r < 4; ++r) {
                const int row = mt * 16 + (lane >> 4) * 4 + r;
                const int col = w * 32 + ntl * 16 + (lane & 15);
                h2[row * 132 + col] = fmaxf(acc2[mt][ntl][r] + b2v[ntl], 0.f);
            }
    __syncthreads();

    // ---- segment sums: 2 half-windows x 128 cols ----
    {
        const int g = t >> 7;
        const int c = t & 127;
        const int base = g * 32;
        const long rb = r0 + base;
        const int prev = (rb == 0) ? -1 : seg[rb - 1];
        const int nxt = (rb + 32 >= R_ROWS) ? -1 : seg[rb + 32];
        int cur = seg[rb];
        float run = 0.f;
        int runstart = 0;
        #pragma unroll 1
        for (int r = 0; r < 32; ++r) {
            const int s = seg[rb + r];
            if (s != cur) {
                if (runstart != 0 || cur != prev) sums[(long)cur * D + c] = run;
                else atomicAdd(&sums[(long)cur * D + c], run);
                cur = s; run = 0.f; runstart = r;
            }
            run += h2[(base + r) * 132 + c];
        }
        if ((runstart != 0 || cur != prev) && cur != nxt) sums[(long)cur * D + c] = run;
        else atomicAdd(&sums[(long)cur * D + c], run);
    }
}

__global__ __launch_bounds__(256) void start_kernel(const int* __restrict__ seg,
                                                    int* __restrict__ start)
{
    const int n = blockIdx.x * 256 + threadIdx.x;
    if (n > NN) return;
    int lo = 0, hi = R_ROWS;
    #pragma unroll 1
    while (lo < hi) {
        const int mid = (lo + hi) >> 1;
        if (seg[mid] < n) lo = mid + 1; else hi = mid;
    }
    start[n] = lo;
}

__global__ __launch_bounds__(256) void divide_bf(
    const float* __restrict__ sums, const int* __restrict__ start,
    uint* __restrict__ hbf)
{
    const long i = (long)blockIdx.x * 256 + threadIdx.x;
    if (i < (long)NN * 64) {
        const int n = (int)(i >> 6), u = (int)(i & 63);
        const int cA = (u & 15) + (u >> 4) * 32;
        const float inv = 1.f / fmaxf((float)(start[n + 1] - start[n]), 1.f);
        const float vA = sums[(long)n * D + cA] * inv;
        const float vB = sums[(long)n * D + cA + 16] * inv;
        hbf[i] = cvtpk(vA, vB);
    }
}

__global__ __launch_bounds__(256) void hist_kernel(const int* __restrict__ edst,
                                                   int* __restrict__ deg)
{
    const int e = blockIdx.x * 256 + threadIdx.x;
    if (e < NE) atomicAdd(&deg[edst[e]], 1);
}

#define SCHUNK 2048
__global__ __launch_bounds__(256) void scan_reduce(const int* __restrict__ deg,
                                                   int* __restrict__ partials, int n)
{
    __shared__ int sdata[256];
    const int b = blockIdx.x, t = threadIdx.x;
    const int base = b * SCHUNK;
    int sum = 0;
    for (int i = t; i < SCHUNK; i += 256) {
        const int idx = base + i;
        sum += (idx < n) ? deg[idx] : 0;
    }
    sdata[t] = sum; __syncthreads();
    for (int s = 128; s > 0; s >>= 1) {
        if (t < s) sdata[t] += sdata[t + s];
        __syncthreads();
    }
    if (t == 0) partials[b] = sdata[0];
}

__global__ __launch_bounds__(256) void scan_write(const int* __restrict__ deg,
                                                  const int* __restrict__ partials,
                                                  int nchunks,
                                                  int* __restrict__ offsets,
                                                  int* __restrict__ cursor, int n)
{
    __shared__ int sdata[256];
    __shared__ int base_sh;
    const int b = blockIdx.x, t = threadIdx.x;
    if (t < 64) {
        int v = (t < b && t < nchunks) ? partials[t] : 0;
        #pragma unroll
        for (int d2 = 1; d2 < 64; d2 <<= 1) v += __shfl_xor(v, d2);
        if (t == 0) base_sh = v;
    }
    const int base = b * SCHUNK;
    int loc[8]; int s = 0;
    #pragma unroll
    for (int j = 0; j < 8; ++j) {
        const int idx = base + t * 8 + j;
        const int v = (idx < n) ? deg[idx] : 0;
        loc[j] = s; s += v;
    }
    sdata[t] = s; __syncthreads();
    for (int d = 1; d < 256; d <<= 1) {
        const int v = (t >= d) ? sdata[t - d] : 0;
        __syncthreads();
        sdata[t] += v;
        __syncthreads();
    }
    const int excl = (t == 0) ? 0 : sdata[t - 1];
    const int tbase = base_sh + excl;
    #pragma unroll
    for (int j = 0; j < 8; ++j) {
        const int idx = base + t * 8 + j;
        if (idx < n) {
            const int o = tbase + loc[j];
            offsets[idx] = o;
            cursor[idx] = o;
        }
    }
}

__global__ __launch_bounds__(256) void scatter_edges(const int* __restrict__ esrc,
                                                     const int* __restrict__ edst,
                                                     int* __restrict__ cursor,
                                                     int* __restrict__ csr_src)
{
    const int e = blockIdx.x * 256 + threadIdx.x;
    if (e < NE) {
        const int d = edst[e];
        const int p = atomicAdd(&cursor[d], 1);
        csr_src[p] = esrc[e];
    }
}

// ---------------------------------------------------------------------------
// Fused GIN layer, bf16 h. Half-wave per row gather; W-hi-only MFMA.
// MODE 0: all nodes -> hbf; MODE 2: roots -> compact X buffer.
// ---------------------------------------------------------------------------
template<int MODE>
__global__ __launch_bounds__(256, 8) void gin_kernel(
    const uint* __restrict__ hbf, const int* __restrict__ offsets,
    const int* __restrict__ deg, const int* __restrict__ csr,
    const ushort* __restrict__ Wp, const float* __restrict__ bvec,
    uint* __restrict__ outbuf, const int* __restrict__ root)
{
    __shared__ __align__(16) char ylds[64 * 256];   // 16 KB
    const int t = threadIdx.x, lane = t & 63, w = t >> 6;
    const int h = lane >> 5;
    const int q2 = (lane >> 4) & 1;
    const int m = lane & 15;
    const int q = lane >> 4;
    const int r0 = blockIdx.x * 64;

    #pragma unroll 1
    for (int i = 0; i < 8; ++i) {
        const int row = w * 16 + i * 2 + h;
        int n = -1;
        if (MODE == 0) {
            const int nn = r0 + row;
            if (nn < NN) n = nn;
        } else {
            n = root[r0 + row];
        }
        f32x4 accL = {0.f, 0.f, 0.f, 0.f};
        f32x4 accH = {0.f, 0.f, 0.f, 0.f};
        if (n >= 0) {
            const uintx4 sp = *reinterpret_cast<const uintx4*>(&hbf[(long)n * 64 + 4 * m]);
            const float sc = (q2 == 0) ? 2.1f : 0.f;
            accL[0] = sc * lo16f(sp[0]); accH[0] = sc * hi16f(sp[0]);
            accL[1] = sc * lo16f(sp[1]); accH[1] = sc * hi16f(sp[1]);
            accL[2] = sc * lo16f(sp[2]); accH[2] = sc * hi16f(sp[2]);
            accL[3] = sc * lo16f(sp[3]); accH[3] = sc * hi16f(sp[3]);
            const int off = offsets[n];
            const int dg = deg[n];
            const int dg2 = dg >> 1;
            int jj = 0;
            for (; jj + 4 <= dg2; jj += 4) {
                const int b0 = off + 2 * jj + q2;
                const int s0 = csr[b0], s1 = csr[b0 + 2], s2 = csr[b0 + 4], s3 = csr[b0 + 6];
                const uintx4 p0 = *reinterpret_cast<const uintx4*>(&hbf[(long)s0 * 64 + 4 * m]);
                const uintx4 p1 = *reinterpret_cast<const uintx4*>(&hbf[(long)s1 * 64 + 4 * m]);
                const uintx4 p2 = *reinterpret_cast<const uintx4*>(&hbf[(long)s2 * 64 + 4 * m]);
                const uintx4 p3 = *reinterpret_cast<const uintx4*>(&hbf[(long)s3 * 64 + 4 * m]);
                acc_add(accL, accH, p0);
                acc_add(accL, accH, p1);
                acc_add(accL, accH, p2);
                acc_add(accL, accH, p3);
            }
            for (; jj < dg2; ++jj) {
                const int s = csr[off + 2 * jj + q2];
                const uintx4 p = *reinterpret_cast<const uintx4*>(&hbf[(long)s * 64 + 4 * m]);
                acc_add(accL, accH, p);
            }
            if ((dg & 1) && q2 == 0) {
                const int s = csr[off + dg - 1];
                const uintx4 p = *reinterpret_cast<const uintx4*>(&hbf[(long)s * 64 + 4 * m]);
                acc_add(accL, accH, p);
            }
        }
        #pragma unroll
        for (int e = 0; e < 4; ++e) {
            accL[e] += __shfl_xor(accL[e], 16);
            accH[e] += __shfl_xor(accH[e], 16);
        }
        const int swz = (row & 7) << 4;
        #pragma unroll
        for (int e = 0; e < 2; ++e) {
            const int u = 4 * m + 2 * q2 + e;
            const int cA = (u & 15) + (u >> 4) * 32;
            const uint pk = cvtpk(accL[2 * q2 + e], accH[2 * q2 + e]);
            *reinterpret_cast<ushort*>(ylds + ((row * 256 + cA * 2) ^ swz)) = (ushort)pk;
            *reinterpret_cast<ushort*>(ylds + ((row * 256 + (cA + 16) * 2) ^ swz)) = (ushort)(pk >> 16);
        }
    }

    short8 bw0[2];
    #pragma unroll
    for (int ntl = 0; ntl < 2; ++ntl) {
        const int f = w * 2 + ntl;
        bw0[ntl] = *reinterpret_cast<const short8*>(&Wp[((f * 2 + 0) * 64 + lane) * 8]);
    }
    __syncthreads();

    const f32x4 zz = {0.f, 0.f, 0.f, 0.f};
    f32x4 acc[4][2];
    #pragma unroll
    for (int mt = 0; mt < 4; ++mt) { acc[mt][0] = zz; acc[mt][1] = zz; }

    #pragma unroll
    for (int kt = 0; kt < 4; ++kt) {
        short8 bw[2];
        if (kt == 0) { bw[0] = bw0[0]; bw[1] = bw0[1]; }
        else {
            #pragma unroll
            for (int ntl = 0; ntl < 2; ++ntl) {
                const int f = kt * 8 + (w * 2 + ntl);
                bw[ntl] = *reinterpret_cast<const short8*>(&Wp[((f * 2 + 0) * 64 + lane) * 8]);
            }
        }
        #pragma unroll
        for (int mt = 0; mt < 4; ++mt) {
            const int row = mt * 16 + m;
            const int k0 = kt * 32 + q * 8;
            const short8 ah = *reinterpret_cast<const short8*>(
                ylds + ((row * 256 + k0 * 2) ^ ((row & 7) << 4)));
            acc[mt][0] = mm(ah, bw[0], acc[mt][0]);
            acc[mt][1] = mm(ah, bw[1], acc[mt][1]);
        }
    }

    const float bv0 = bvec[w * 32 + m];
    const float bv1 = bvec[w * 32 + 16 + m];
    #pragma unroll
    for (int mt = 0; mt < 4; ++mt)
        #pragma unroll
        for (int r = 0; r < 4; ++r) {
            const int grow_row = mt * 16 + q * 4 + r;
            const float v0 = fmaxf(acc[mt][0][r] + bv0, 0.f);
            const float v1 = fmaxf(acc[mt][1][r] + bv1, 0.f);
            const uint pk = cvtpk(v0, v1);
            if (MODE == 0) {
                const long nout = r0 + grow_row;
                if (nout < NN) outbuf[nout * 64 + w * 16 + m] = pk;
            } else {
                outbuf[(long)(r0 + grow_row) * 64 + w * 16 + m] = pk;
            }
        }
}

// ---------------------------------------------------------------------------
// MFMA batch heads: 64 blocks x 64 roots. Full hi+lo split for head weights.
// ---------------------------------------------------------------------------
__global__ __launch_bounds__(256) void head_mfma(
    const uint* __restrict__ Xbf,
    const ushort* __restrict__ Wa1p, const float* __restrict__ ba1,
    const ushort* __restrict__ Wa2p, const float* __restrict__ ba2,
    const ushort* __restrict__ Wc1p, const float* __restrict__ bc1,
    const float* __restrict__ Wc2, const float* __restrict__ bc2,
    float* __restrict__ out_act, float* __restrict__ out_crit)
{
    __shared__ __align__(16) char Xp[64 * 256];    // 16 KB
    __shared__ __align__(16) char a1p[64 * 512];   // 32 KB
    const int t = threadIdx.x, lane = t & 63, w = t >> 6;
    const int r0 = blockIdx.x * 64;
    const f32x4 zz = {0.f, 0.f, 0.f, 0.f};

    {
        const int row = t >> 2;
        const int ug = (t & 3) * 16;
        const int swz = (row & 7) << 4;
        #pragma unroll
        for (int uu = 0; uu < 16; ++uu) {
            const uint pk = Xbf[(long)(r0 + row) * 64 + ug + uu];
            const int u = ug + uu;
            const int cA = (u & 15) + (u >> 4) * 32;
            *reinterpret_cast<ushort*>(Xp + ((row * 256 + cA * 2) ^ swz)) = (ushort)pk;
            *reinterpret_cast<ushort*>(Xp + ((row * 256 + (cA + 16) * 2) ^ swz)) = (ushort)(pk >> 16);
        }
    }
    __syncthreads();

    {
        f32x4 acc1[4][4];
        #pragma unroll
        for (int mtl = 0; mtl < 4; ++mtl)
            #pragma unroll
            for (int ntb = 0; ntb < 4; ++ntb) acc1[mtl][ntb] = zz;
        #pragma unroll
        for (int kt = 0; kt < 4; ++kt) {
            short8 aw[4][2];
            #pragma unroll
            for (int mtl = 0; mtl < 4; ++mtl)
                #pragma unroll
                for (int p = 0; p < 2; ++p) {
                    const int f = kt * 16 + (w * 4 + mtl);
                    aw[mtl][p] = *reinterpret_cast<const short8*>(&Wa1p[((f * 2 + p) * 64 + lane) * 8]);
                }
            short8 bh[4];
            #pragma unroll
            for (int ntb = 0; ntb < 4; ++ntb) {
                const int row = ntb * 16 + (lane & 15);
                const int k0 = kt * 32 + (lane >> 4) * 8;
                bh[ntb] = *reinterpret_cast<const short8*>(Xp + ((row * 256 + k0 * 2) ^ ((row & 7) << 4)));
            }
            #pragma unroll
            for (int mtl = 0; mtl < 4; ++mtl)
                #pragma unroll
                for (int ntb = 0; ntb < 4; ++ntb) {
                    acc1[mtl][ntb] = mm(aw[mtl][0], bh[ntb], acc1[mtl][ntb]);
                    acc1[mtl][ntb] = mm(aw[mtl][1], bh[ntb], acc1[mtl][ntb]);
                }
        }
        #pragma unroll
        for (int mtl = 0; mtl < 4; ++mtl) {
            const int hcb = w * 64 + mtl * 16 + (lane >> 4) * 4;
            const float4 bv = *reinterpret_cast<const float4*>(&ba1[hcb]);
            #pragma unroll
            for (int ntb = 0; ntb < 4; ++ntb) {
                const int hr = (lane & 15) + ntb * 16;
                const float v0 = fmaxf(acc1[mtl][ntb][0] + bv.x, 0.f);
                const float v1 = fmaxf(acc1[mtl][ntb][1] + bv.y, 0.f);
                const float v2 = fmaxf(acc1[mtl][ntb][2] + bv.z, 0.f);
                const float v3 = fmaxf(acc1[mtl][ntb][3] + bv.w, 0.f);
                uint2 pk; pk.x = cvtpk(v0, v1); pk.y = cvtpk(v2, v3);
                const int byteoff = (hr * 512 + hcb * 2) ^ ((hr & 7) << 4);
                *reinterpret_cast<uint2*>(a1p + byteoff) = pk;
            }
        }
    }
    __syncthreads();

    {
        f32x4 accl = zz;
        #pragma unroll
        for (int kt = 0; kt < 8; ++kt) {
            short8 b2h = *reinterpret_cast<const short8*>(&Wa2p[((kt * 2 + 0) * 64 + lane) * 8]);
            short8 b2l = *reinterpret_cast<const short8*>(&Wa2p[((kt * 2 + 1) * 64 + lane) * 8]);
            const int row = w * 16 + (lane & 15);
            const int k0 = kt * 32 + (lane >> 4) * 8;
            const short8 ah = *reinterpret_cast<const short8*>(a1p + ((row * 512 + k0 * 2) ^ ((row & 7) << 4)));
            accl = mm(ah, b2h, accl);
            accl = mm(ah, b2l, accl);
        }
        const int j = lane & 15;
        float lg[4], sm[4];
        #pragma unroll
        for (int r = 0; r < 4; ++r) {
            lg[r] = fmaxf(accl[r] + ba2[j], 0.f);
            float m2 = lg[r];
            #pragma unroll
            for (int d2 = 1; d2 < 16; d2 <<= 1) m2 = fmaxf(m2, __shfl_xor(m2, d2));
            lg[r] = expf(lg[r] - m2);
            float s2 = lg[r];
            #pragma unroll
            for (int d2 = 1; d2 < 16; d2 <<= 1) s2 += __shfl_xor(s2, d2);
            sm[r] = s2;
        }
        #pragma unroll
        for (int r = 0; r < 4; ++r) {
            const int root_slot = r0 + w * 16 + (lane >> 4) * 4 + r;
            out_act[(long)root_slot * NTOK + j] = lg[r] / sm[r];
        }
    }
    __syncthreads();

    {
        f32x4 acc1[4][4];
        #pragma unroll
        for (int mtl = 0; mtl < 4; ++mtl)
            #pragma unroll
            for (int ntb = 0; ntb < 4; ++ntb) acc1[mtl][ntb] = zz;
        #pragma unroll
        for (int kt = 0; kt < 4; ++kt) {
            short8 aw[4][2];
            #pragma unroll
            for (int mtl = 0; mtl < 4; ++mtl)
                #pragma unroll
                for (int p = 0; p < 2; ++p) {
                    const int f = kt * 16 + (w * 4 + mtl);
                    aw[mtl][p] = *reinterpret_cast<const short8*>(&Wc1p[((f * 2 + p) * 64 + lane) * 8]);
                }
            short8 bh[4];
            #pragma unroll
            for (int ntb = 0; ntb < 4; ++ntb) {
                const int row = ntb * 16 + (lane & 15);
                const int k0 = kt * 32 + (lane >> 4) * 8;
                bh[ntb] = *reinterpret_cast<const short8*>(Xp + ((row * 256 + k0 * 2) ^ ((row & 7) << 4)));
            }
            #pragma unroll
            for (int mtl = 0; mtl < 4; ++mtl)
                #pragma unroll
                for (int ntb = 0; ntb < 4; ++ntb) {
                    acc1[mtl][ntb] = mm(aw[mtl][0], bh[ntb], acc1[mtl][ntb]);
                    acc1[mtl][ntb] = mm(aw[mtl][1], bh[ntb], acc1[mtl][ntb]);
                }
        }
        #pragma unroll
        for (int mtl = 0; mtl < 4; ++mtl) {
            const int hcb = w * 64 + mtl * 16 + (lane >> 4) * 4;
            const float4 bv = *reinterpret_cast<const float4*>(&bc1[hcb]);
            #pragma unroll
            for (int ntb = 0; ntb < 4; ++ntb) {
                const int hr = (lane & 15) + ntb * 16;
                const float v0 = fmaxf(acc1[mtl][ntb][0] + bv.x, 0.f);
                const float v1 = fmaxf(acc1[mtl][ntb][1] + bv.y, 0.f);
                const float v2 = fmaxf(acc1[mtl][ntb][2] + bv.z, 0.f);
                const float v3 = fmaxf(acc1[mtl][ntb][3] + bv.w, 0.f);
                uint2 pk; pk.x = cvtpk(v0, v1); pk.y = cvtpk(v2, v3);
                const int byteoff = (hr * 512 + hcb * 2) ^ ((hr & 7) << 4);
                *reinterpret_cast<uint2*>(a1p + byteoff) = pk;
            }
        }
    }
    __syncthreads();

    {
        const int row = w * 16 + (lane & 15);
        const int qk = lane >> 4;
        float dot = 0.f;
        #pragma unroll
        for (int g = 0; g < 8; ++g) {
            const int k0 = qk * 64 + g * 8;
            const short8 av = *reinterpret_cast<const short8*>(a1p + ((row * 512 + k0 * 2) ^ ((row & 7) << 4)));
            #pragma unroll
            for (int e = 0; e < 8; ++e)
                dot = fmaf(bf2f((ushort)av[e]), Wc2[k0 + e], dot);
        }
        dot += __shfl_xor(dot, 16);
        dot += __shfl_xor(dot, 32);
        if (lane < 16) out_crit[r0 + w * 16 + lane] = dot + bc2[0];
    }
}

// ---------------------------------------------------------------------------
extern "C" void kernel_launch(void* const* d_in, const int* in_sizes, int n_in,
                              void* d_out, int out_size, void* d_ws, size_t ws_size,
                              hipStream_t stream)
{
    const float* bulk = (const float*)d_in[0];
    const int*   seg  = (const int*)d_in[1];
    const int*   esrc = (const int*)d_in[2];
    const int*   edst = (const int*)d_in[3];
    const int*   root = (const int*)d_in[4];
    const float* W1   = (const float*)d_in[6];
    const float* b1   = (const float*)d_in[7];
    const float* W2   = (const float*)d_in[8];
    const float* b2   = (const float*)d_in[9];
    const float* ginW = (const float*)d_in[10];
    const float* ginb = (const float*)d_in[11];
    const float* Wa1  = (const float*)d_in[12];
    const float* ba1  = (const float*)d_in[13];
    const float* Wa2  = (const float*)d_in[14];
    const float* ba2  = (const float*)d_in[15];
    const float* Wc1  = (const float*)d_in[16];
    const float* bc1  = (const float*)d_in[17];
    const float* Wc2  = (const float*)d_in[18];
    const float* bc2  = (const float*)d_in[19];

    char* ws = (char*)d_ws;
    ushort* W1p = (ushort*)ws;                     // 64 KB
    ushort* W2p = W1p + 32768;                     // 128 KB
    float* sums    = (float*)(ws + 196608);        // N*D f32
    uint*  hbfA    = (uint*)(sums + (long)NN * D); // N*64
    uint*  hbfB    = hbfA + (long)NN * 64;         // N*64
    int*   start   = (int*)(hbfB + (long)NN * 64); // N+4
    int*   deg     = start + (NN + 4);             // N
    int*   offsets = deg + NN;                     // N
    int*   cursor  = offsets + NN;                 // N
    int*   partials= cursor + NN;                  // 256
    int*   csr     = partials + 256;               // E
    uint*  Xbf     = (uint*)(csr + NE);            // NB*64
    ushort* Gp     = (ushort*)(Xbf + (long)NB * 64); // 256 KB
    ushort* Wa1p   = Gp + 4 * 32768;               // 128 KB
    ushort* Wc1p   = Wa1p + 65536;                 // 128 KB
    ushort* Wa2p   = Wc1p + 65536;                 // 16 KB

    hipMemsetAsync(sums, 0, (long)NN * D * sizeof(float), stream);

    pack_all<<<188, 256, 0, stream>>>(W1, W2, ginW, Wa1, Wc1, Wa2,
                                      W1p, W2p, Gp, Wa1p, Wc1p, Wa2p, deg);

    fe_mfma<<<R_ROWS / FE_ROWS, 256, 0, stream>>>(bulk, seg, W1p, b1, W2p, b2, sums);
    start_kernel<<<(NN + 256) / 256, 256, 0, stream>>>(seg, start);
    divide_bf<<<((long)NN * 64 + 255) / 256, 256, 0, stream>>>(sums, start, hbfA);

    hist_kernel<<<(NE + 255) / 256, 256, 0, stream>>>(edst, deg);
    const int nchunks = (NN + SCHUNK - 1) / SCHUNK;
    scan_reduce<<<nchunks, 256, 0, stream>>>(deg, partials, NN);
    scan_write<<<nchunks, 256, 0, stream>>>(deg, partials, nchunks, offsets, cursor, NN);
    scatter_edges<<<(NE + 255) / 256, 256, 0, stream>>>(esrc, edst, cursor, csr);

    const int full_grid = (NN + 63) / 64;
    gin_kernel<0><<<full_grid, 256, 0, stream>>>(hbfA, offsets, deg, csr,
        Gp + 0L * 32768, ginb + 0L * D, hbfB, root);
    gin_kernel<0><<<full_grid, 256, 0, stream>>>(hbfB, offsets, deg, csr,
        Gp + 1L * 32768, ginb + 1L * D, hbfA, root);
    gin_kernel<0><<<full_grid, 256, 0, stream>>>(hbfA, offsets, deg, csr,
        Gp + 2L * 32768, ginb + 2L * D, hbfB, root);
    gin_kernel<2><<<NB / 64, 256, 0, stream>>>(hbfB, offsets, deg, csr,
        Gp + 3L * 32768, ginb + 3L * D, Xbf, root);

    head_mfma<<<NB / 64, 256, 0, stream>>>(Xbf, Wa1p, ba1, Wa2p, ba2,
                                           Wc1p, bc1, Wc2, bc2,
                                           (float*)d_out, (float*)d_out + (long)NB * NTOK);
}